// Round 1
// 448.207 us; speedup vs baseline: 1.0742x; 1.0742x over previous
//
#include <hip/hip_runtime.h>
#include <math.h>

// ws layout (floats):
//   ws[0 .. NBLK)          per-block partial sums of squares (matrix segments)
//   ws[NBLK .. NBLK+128)   per-row bias norms
// Every slot written exactly once per launch: no atomics, no zero-init.

// ext_vector float4 so __builtin_nontemporal_load accepts it (HIP's float4 is a
// struct, which the builtin rejects). Loads are read-once, and the harness's
// 1 GB workspace poison flushes L2/L3 between iterations anyway -> nt (stream)
// loads skip cache allocation, avoiding L2 tag churn across 7 concurrent
// matrix streams.
typedef float vf4 __attribute__((ext_vector_type(4)));

struct MatArgs {
    const float* ptr[7];
    unsigned blk_off[8];  // cumulative block counts per matrix; blk_off[7] = NBLK
};

#define BLOCK 256
#define K_ITERS 64              // float4 per thread; 16384 floats per block total
#define F4_PER_BLOCK (BLOCK * K_ITERS)
#define NBIAS 128

__device__ __forceinline__ float block_reduce_sum(float s, float* lsum) {
    #pragma unroll
    for (int off = 32; off > 0; off >>= 1)
        s += __shfl_down(s, off, 64);
    const int lane = threadIdx.x & 63;
    const int wave = threadIdx.x >> 6;
    if (lane == 0) lsum[wave] = s;
    __syncthreads();
    float t = 0.0f;
    if (threadIdx.x == 0) {
        #pragma unroll
        for (int w = 0; w < BLOCK / 64; ++w) t += lsum[w];
    }
    __syncthreads();
    return t;  // valid on thread 0 only
}

// Grid-stride WITHIN each matrix: at iteration k, all blocks of matrix m read one
// contiguous window (B_m * 4 KB) that sweeps forward -> dense DRAM front, like a
// memcpy. (Chunk-per-block mapping measured only ~1.4 TB/s HBM: row thrash.)
// Unroll stays at 8: keeps VGPR low enough for 8 blocks/CU so all ~1896 blocks
// are co-resident (one dispatch wave, minimal tail).
__global__ __launch_bounds__(BLOCK) void sumsq_kernel(MatArgs a,
                                                      const float* __restrict__ biases,
                                                      float* __restrict__ ws) {
    __shared__ float lsum[BLOCK / 64];
    const unsigned nblk = a.blk_off[7];
    const unsigned b = blockIdx.x;

    if (b < nblk) {
        int m = 0;
        #pragma unroll
        for (int i = 1; i < 7; ++i)
            if (b >= a.blk_off[i]) m = i;
        const unsigned lb = b - a.blk_off[m];
        const unsigned Bm = a.blk_off[m + 1] - a.blk_off[m];
        const vf4* __restrict__ p = (const vf4*)a.ptr[m];

        size_t idx = (size_t)lb * BLOCK + threadIdx.x;
        const size_t stride = (size_t)Bm * BLOCK;

        float s0 = 0.0f, s1 = 0.0f, s2 = 0.0f, s3 = 0.0f;
        #pragma unroll 8
        for (int k = 0; k < K_ITERS; ++k) {
            vf4 v = __builtin_nontemporal_load(p + idx + (size_t)k * stride);
            s0 += v.x * v.x;
            s1 += v.y * v.y;
            s2 += v.z * v.z;
            s3 += v.w * v.w;
        }
        float t = block_reduce_sum((s0 + s1) + (s2 + s3), lsum);
        if (threadIdx.x == 0) ws[b] = t;
    } else {
        // bias row: 2048 floats -> L2 norm, one block per row
        const unsigned row = b - nblk;
        const vf4* __restrict__ p =
            (const vf4*)(biases + (size_t)row * 2048) + threadIdx.x;
        vf4 v0 = __builtin_nontemporal_load(p);
        vf4 v1 = __builtin_nontemporal_load(p + BLOCK);
        float s = v0.x * v0.x + v0.y * v0.y + v0.z * v0.z + v0.w * v0.w +
                  v1.x * v1.x + v1.y * v1.y + v1.z * v1.z + v1.w * v1.w;
        float t = block_reduce_sum(s, lsum);
        if (threadIdx.x == 0) ws[b] = sqrtf(t);
    }
}

__global__ __launch_bounds__(BLOCK) void finalize_kernel(MatArgs a,
                                                         const float* __restrict__ ws,
                                                         float* __restrict__ out) {
    __shared__ float lsum[BLOCK / 64];
    __shared__ float l2_acc;
    if (threadIdx.x == 0) l2_acc = 0.0f;
    __syncthreads();

    const unsigned nblk = a.blk_off[7];
    #pragma unroll
    for (int m = 0; m < 7; ++m) {
        float s = 0.0f;
        for (unsigned i = a.blk_off[m] + threadIdx.x; i < a.blk_off[m + 1]; i += BLOCK)
            s += ws[i];
        float t = block_reduce_sum(s, lsum);
        if (threadIdx.x == 0) l2_acc += sqrtf(t);
    }
    {
        float s = 0.0f;
        for (unsigned i = nblk + threadIdx.x; i < nblk + NBIAS; i += BLOCK)
            s += ws[i];
        float t = block_reduce_sum(s, lsum);
        if (threadIdx.x == 0) l2_acc += t;
    }
    if (threadIdx.x == 0)
        out[0] = 0.0001f * (l2_acc / 135.0f);
}

extern "C" void kernel_launch(void* const* d_in, const int* in_sizes, int n_in,
                              void* d_out, int out_size, void* d_ws, size_t ws_size,
                              hipStream_t stream) {
    float* ws = (float*)d_ws;
    float* out = (float*)d_out;

    MatArgs a;
    unsigned total_blocks = 0;
    a.blk_off[0] = 0;
    for (int i = 0; i < 7; ++i) {
        a.ptr[i] = (const float*)d_in[i];
        unsigned n4 = (unsigned)(in_sizes[i] / 4);
        // All sizes are exact multiples of F4_PER_BLOCK (=16384 f4):
        // 2048*2048 -> 64 blocks, 2048*8192 -> 256, 32000*2048 -> 1000.
        unsigned blocks = n4 / F4_PER_BLOCK;
        total_blocks += blocks;
        a.blk_off[i + 1] = total_blocks;
    }
    const float* biases = (const float*)d_in[7];

    sumsq_kernel<<<total_blocks + NBIAS, BLOCK, 0, stream>>>(a, biases, ws);
    finalize_kernel<<<1, BLOCK, 0, stream>>>(a, ws, out);
}